// Round 14
// baseline (6835.804 us; speedup 1.0000x reference)
//
#include <hip/hip_runtime.h>
#include <cstdio>
#include <cstdint>

typedef unsigned short u16;
typedef unsigned int u32;
typedef float f32x4 __attribute__((ext_vector_type(4)));
typedef short s16x8 __attribute__((ext_vector_type(8)));
typedef int i32x2 __attribute__((ext_vector_type(2)));

#define DI __device__ __forceinline__

// problem sizes
#define BATCH 32
#define SEQT 512
#define HDIM 1024
#define PDIM 512
#define DEMB 512
#define G4H 4096

// ---------------- bf16 helpers (RNE + hi/lo split) ----------------
DI u16 f2bf(float f) {
  u32 u = __float_as_uint(f);
  return (u16)((u + 0x7fffu + ((u >> 16) & 1u)) >> 16);
}
DI float bf2f(u16 h) { return __uint_as_float(((u32)h) << 16); }
DI void split2(float f, u16 &hi, u16 &lo) {
  hi = f2bf(f);
  lo = f2bf(f - bf2f(hi));  // exact residual capture to ~2^-17 rel
}
DI f32x4 mfma16(s16x8 a, s16x8 b, f32x4 c) {
  return __builtin_amdgcn_mfma_f32_16x16x32_bf16(a, b, c, 0, 0, 0);
}
DI void dma16(const void *g, void *l) {
  __builtin_amdgcn_global_load_lds((const __attribute__((address_space(1))) void *)g,
                                   (__attribute__((address_space(3))) void *)l, 16, 0, 0);
}
// device-scope (sc1) ops: bypass L1/L2, talk straight to the coherence point.
// RULE-18/20 DISCIPLINE: asm-load outputs consumed right after vmcnt(0)+
// sched_barrier(0). R12 LESSON: no per-lane LDS atomics on the critical path.
DI s16x8 ld128_dev(const u16 *p) {
  s16x8 r;
  asm volatile("global_load_dwordx4 %0, %1, off sc1" : "=v"(r) : "v"(p));
  return r;
}
DI i32x2 ld64_dev(const u16 *p) {
  i32x2 r;
  asm volatile("global_load_dwordx2 %0, %1, off sc1" : "=v"(r) : "v"(p));
  return r;
}
DI void st32_dev(int *p, int v) {
  asm volatile("global_store_dword %0, %1, off sc1" ::"v"(p), "v"(v) : "memory");
}
DI void st64_dev(u16 *p, i32x2 v) {
  asm volatile("global_store_dwordx2 %0, %1, off sc1" ::"v"(p), "v"(v) : "memory");
}
// sentinel detector: any bf16 lane == 0xFFFF (unreachable from f2bf(finite))
DI u32 sentq(s16x8 v) {
  union U { s16x8 s; u32 d[4]; } u;
  u.s = v;
  u32 b = 0;
#pragma unroll
  for (int i = 0; i < 4; ++i)
    b |= (u32)(((u.d[i] & 0xffffu) == 0xffffu) || ((u.d[i] >> 16) == 0xffffu));
  return b;
}

// fast gate math: hardware exp2 + rcp (~1e-7 abs err on sigmoid/tanh outputs)
#if __has_builtin(__builtin_amdgcn_exp2f) && __has_builtin(__builtin_amdgcn_rcpf)
DI float fsig(float x) {
  return __builtin_amdgcn_rcpf(1.f + __builtin_amdgcn_exp2f(-1.4426950408889634f * x));
}
DI float ftanh(float x) {
  return 2.f * __builtin_amdgcn_rcpf(1.f + __builtin_amdgcn_exp2f(-2.8853900817779268f * x)) - 1.f;
}
#else
DI float fsig(float x) { return 1.f / (1.f + expf(-x)); }
DI float ftanh(float x) { return tanhf(x); }
#endif

// ---------------- embed gather -> x0 hi/lo planes ----------------
__global__ void k_gather_pack(const int *__restrict__ tokens, const float *__restrict__ embed,
                              u16 *__restrict__ xhi, u16 *__restrict__ xlo) {
  int idx = blockIdx.x * 256 + threadIdx.x;  // one thread per 8 elements
  int m = idx >> 6;                          // row 0..16383 (m = b*T + t)
  int k8 = (idx & 63) << 3;
  int tok = tokens[m];
  const float *src = embed + (size_t)tok * DEMB + k8;
  float4 a = *(const float4 *)src;
  float4 b = *(const float4 *)(src + 4);
  float v[8] = {a.x, a.y, a.z, a.w, b.x, b.y, b.z, b.w};
  union UV { u16 h[8]; int4 v; };
  UV uh, ul;
#pragma unroll
  for (int j = 0; j < 8; ++j) split2(v[j], uh.h[j], ul.h[j]);
  size_t o = (size_t)m * DEMB + k8;
  *(int4 *)(xhi + o) = uh.v;
  *(int4 *)(xlo + o) = ul.v;
}

// ------- transpose+split weights: W[K][N] f32 -> T[N][K] bf16 hi/lo -------
__global__ void k_packT(const float *__restrict__ W, u16 *__restrict__ Thi, u16 *__restrict__ Tlo,
                        int K, int N) {
  __shared__ float tile[32][33];
  int n0 = blockIdx.x * 32, k0 = blockIdx.y * 32;
  int tx = threadIdx.x, ty = threadIdx.y;  // (32,8)
#pragma unroll
  for (int i = 0; i < 4; ++i) tile[ty + 8 * i][tx] = W[(size_t)(k0 + ty + 8 * i) * N + n0 + tx];
  __syncthreads();
#pragma unroll
  for (int i = 0; i < 4; ++i) {
    int n = ty + 8 * i;
    u16 hi, lo;
    split2(tile[tx][n], hi, lo);
    size_t o = (size_t)(n0 + n) * K + k0 + tx;
    Thi[o] = hi;
    Tlo[o] = lo;
  }
}

// ------- elementwise hi/lo split (row-major, no transpose) -------
__global__ void k_split(const float *__restrict__ W, u16 *__restrict__ hi, u16 *__restrict__ lo,
                        int n) {
  int i = blockIdx.x * 256 + threadIdx.x;
  if (i < n) split2(W[i], hi[i], lo[i]);
}

// ------- beff = bfc0 @ Wx1 + b1  (f32 [4096]) -------
__global__ void k_beff(const float *__restrict__ bfc0, const float *__restrict__ Wx1,
                       const float *__restrict__ b1, float *__restrict__ beff) {
  int n = blockIdx.x * 256 + threadIdx.x;  // 4096
  float acc = b1[n];
  for (int j = 0; j < PDIM; ++j) acc += bfc0[j] * Wx1[(size_t)j * G4H + n];
  beff[n] = acc;
}

// ---------------- generic bf16x3 GEMM ----------------
template <int OM, int SA>
__global__ __launch_bounds__(256, 2) void k_gemm(const u16 *__restrict__ Ahi, const u16 *__restrict__ Alo,
                                                 const u16 *__restrict__ Bhi, const u16 *__restrict__ Blo,
                                                 const float *__restrict__ bias, void *__restrict__ out0,
                                                 int M, int N, int K) {
  __shared__ u16 sP[4][128 * 64];  // planes: Ahi, Alo, Bhi, Blo (16KB each)
  const int tid = threadIdx.x;
  const int w = tid >> 6, lane = tid & 63;
  const int la15 = lane & 15, la4 = lane >> 4;
  const int nbn = N >> 7;
  const int bm = blockIdx.x / nbn, bn = blockIdx.x % nbn;
  const u16 *src = (w == 0) ? Ahi : (w == 1) ? Alo : (w == 2) ? Bhi : Blo;
  const int rowbase = (w < 2) ? bm * 128 : bn * 128;
  char *lds = (char *)&sP[w][0];

  if (SA) {  // zero the Alo plane once; its MFMAs then contribute +0
    for (int i = tid; i < 2048; i += 256) ((unsigned long long *)&sP[1][0])[i] = 0ULL;
  }

  f32x4 acc[2][8] = {};
  for (int kb = 0; kb < K; kb += 64) {
    if (!(SA && w == 1)) {
#pragma unroll
      for (int i = 0; i < 16; ++i) {
        int s = i * 64 + lane;            // 16B slot id
        int row = s >> 3;                 // 8 slots per 128B row
        int k16 = (s & 7) ^ (row & 7);    // inverse of read swizzle
        dma16(src + (size_t)(rowbase + row) * K + kb + k16 * 8, lds + i * 1024);
      }
    }
    asm volatile("s_waitcnt vmcnt(0)" ::: "memory");
    __syncthreads();
#pragma unroll
    for (int ksl = 0; ksl < 2; ++ksl) {
      s16x8 ah[2], al[2];
#pragma unroll
      for (int rf = 0; rf < 2; ++rf) {
        int row = 32 * w + 16 * rf + la15;
        int slot = row * 8 + ((4 * ksl + la4) ^ (row & 7));
        ah[rf] = *(const s16x8 *)((const char *)&sP[0][0] + slot * 16);
        al[rf] = *(const s16x8 *)((const char *)&sP[1][0] + slot * 16);
      }
#pragma unroll
      for (int cf = 0; cf < 8; ++cf) {
        int col = 16 * cf + la15;
        int slot = col * 8 + ((4 * ksl + la4) ^ (col & 7));
        s16x8 bh = *(const s16x8 *)((const char *)&sP[2][0] + slot * 16);
        s16x8 bl = *(const s16x8 *)((const char *)&sP[3][0] + slot * 16);
#pragma unroll
        for (int rf = 0; rf < 2; ++rf) {
          acc[rf][cf] = mfma16(ah[rf], bh, acc[rf][cf]);
          acc[rf][cf] = mfma16(ah[rf], bl, acc[rf][cf]);
          acc[rf][cf] = mfma16(al[rf], bh, acc[rf][cf]);
        }
      }
    }
    __syncthreads();
  }
#pragma unroll
  for (int rf = 0; rf < 2; ++rf) {
#pragma unroll
    for (int cf = 0; cf < 8; ++cf) {
      int c = bn * 128 + 16 * cf + la15;
      float bv = bias ? bias[c] : 0.f;
#pragma unroll
      for (int q = 0; q < 4; ++q) {
        int r = bm * 128 + 32 * w + 16 * rf + 4 * la4 + q;
        float v = acc[rf][cf][q] + bv;
        if (OM == 0) {
          ((u16 *)out0)[(size_t)r * N + c] = f2bf(v);
        } else {
          int b2 = r & 31, tt = r >> 5;  // A rows are m = t*32 + b
          ((float *)out0)[((size_t)b2 * SEQT + tt) * PDIM + c] = v;
        }
      }
    }
  }
}

// ---------------- pipelined 2-layer persistent LSTM recurrence (R14) ----------------
// ZERO-SYNC SLOTS: each WAVE is a self-contained recurrence engine. WG = 128
// threads = 2 INDEPENDENT waves (rg = 0/1: 16 batch rows each); wave owns its
// full K=1024 (2 phases x 16 ld128, regs reused) -> no cross-wave reduction,
// no __syncthreads in the main loop (only the one after weight staging). The
// single-wave fragment->gate exchange uses per-wave LDS (compiler-inserted
// lgkmcnt only). zeff is single-producer/single-consumer: L0 wave (g,rg)
// dumps its COMPLETE 16x32 fragments (no reduce) as 2 coalesced st64/lane;
// L1 wave (g,rg) reads the same fragment layout and folds into its own acc.
// Handshake: h via sentinel speculation (R11); zeff via one flag word per
// wave pair (monotonic); ring 16 deep, backpressure every 8 steps.
__global__ __launch_bounds__(128, 1) void k_recur_pipe(
    const u16 *__restrict__ xz0, const float *__restrict__ Wh0, const float *__restrict__ Wh1,
    const u16 *__restrict__ Weff, const float *__restrict__ beff,
    u16 *h0h, u16 *h1h, u16 *zeffR, int *flags) {
  __shared__ u16 sW[32 * 1024];       // 64 KB: layer's Wh slice [zc][k] swizzled
  __shared__ u16 sE[32 * 1024];       // 64 KB: L0's Weff slice (unused by L1)
  __shared__ float zex[2][16][33];    // per-wave z exchange [rg][row][zc]
  const int tid = threadIdx.x;
  const int rg = tid >> 6, lane = tid & 63;
  const int la15 = lane & 15, la4 = lane >> 4;
  const int wg = blockIdx.x;
  const int layer = wg >> 7;
  const int g = wg & 127;  // 8 h-cols: [8g, 8g+8)

  // stage weights (single bf16, swizzled), once per launch
  const float *Wh = layer ? Wh1 : Wh0;
  for (int i2 = tid; i2 < 32 * 1024; i2 += 128) {
    int zc = i2 & 31;
    int k = i2 >> 5;
    int gcol = (zc >> 3) * HDIM + 8 * g + (zc & 7);
    int boff = zc * 2048 + ((((k >> 3) ^ (zc & 7))) << 4) + (k & 7) * 2;
    *(u16 *)((char *)sW + boff) = f2bf(Wh[(size_t)k * G4H + gcol]);
    if (!layer) *(u16 *)((char *)sE + boff) = Weff[(size_t)k * G4H + gcol];
  }
  __syncthreads();  // the ONLY block-wide barrier

  // gate coords: lane handles 2 cells: local row = lane>>2 (0..15),
  // cols c = (lane&3)*2 + {0,1}; global row = 16*rg + lrow.
  const int lrow = lane >> 2, c0 = (lane & 3) * 2;
  const int grow = 16 * rg + lrow;
  const int fid = g * 2 + rg;  // this wave's flag/ring pair index
  float cst[2] = {0.f, 0.f};   // cell states (registers)

  if (!layer) {
    // ---------------- layer 0 wave (513 slots) ----------------
    for (int t = 0; t <= SEQT; ++t) {
      const bool last = (t == SEQT);
      // prefetch xz (8 scalars: 2 cells x 4 gates; normal cached loads)
      float xzv[2][4];
      if (!last) {
        const u16 *px = xz0 + ((size_t)grow * SEQT + t) * G4H + 8 * g;
#pragma unroll
        for (int ci = 0; ci < 2; ++ci)
#pragma unroll
          for (int gi = 0; gi < 4; ++gi) xzv[ci][gi] = bf2f(px[gi * HDIM + c0 + ci]);
      }
      // ring backpressure every 8 steps (single word, own consumer's flag)
      if ((t & 7) == 0 && t >= 16) {
        const int *f1 = flags + 256 + fid;
        const int bp = t - 9;
        for (long tries = 0;; ++tries) {
          int v = __hip_atomic_load(f1, __ATOMIC_RELAXED, __HIP_MEMORY_SCOPE_AGENT);
          if (v >= bp) break;
          if (tries > (1L << 22)) break;  // safety valve
          __builtin_amdgcn_s_sleep(1);
        }
      }
      if (t > 0) {
        const u16 *pA = h0h + ((size_t)(t - 1) * 32 + 16 * rg) * HDIM;
        f32x4 accW[2] = {}, accE[2] = {};
#pragma unroll
        for (int ph = 0; ph < 2; ++ph) {
          s16x8 aw[16];
          for (long tries = 0;; ++tries) {  // sentinel spec-load, per wave
#pragma unroll
            for (int i = 0; i < 16; ++i)
              aw[i] = ld128_dev(pA + (size_t)la15 * HDIM + 512 * ph + 32 * i + 8 * la4);
            asm volatile("s_waitcnt vmcnt(0)" ::: "memory");
            __builtin_amdgcn_sched_barrier(0);  // rule 18
            u32 bad = 0;
#pragma unroll
            for (int i = 0; i < 16; ++i) bad |= sentq(aw[i]);
            if (__all(bad == 0)) break;
            if (tries > (1L << 17)) break;  // safety valve
            __builtin_amdgcn_s_sleep(2);
          }
#pragma unroll
          for (int i = 0; i < 16; ++i) {
#pragma unroll
            for (int cf = 0; cf < 2; ++cf) {
              int zc = 16 * cf + la15;
              int sl = (4 * (16 * ph + i) + la4) ^ (zc & 7);
              int boff = zc * 2048 + (sl << 4);
              if (!last) accW[cf] = mfma16(aw[i], *(const s16x8 *)((const char *)sW + boff), accW[cf]);
              accE[cf] = mfma16(aw[i], *(const s16x8 *)((const char *)sE + boff), accE[cf]);
            }
          }
        }
        // zeff fragment dump (complete values, no reduce): 2 st64/lane
        u16 *zb = zeffR + (((size_t)((t - 1) & 15) * 256 + fid) << 9);
#pragma unroll
        for (int cf = 0; cf < 2; ++cf) {
          i32x2 pk;
          pk[0] = (int)(((u32)f2bf(accE[cf][1]) << 16) | (u32)f2bf(accE[cf][0]));
          pk[1] = (int)(((u32)f2bf(accE[cf][3]) << 16) | (u32)f2bf(accE[cf][2]));
          st64_dev(zb + (cf << 8) + (lane << 2), pk);
        }
        // own-wave z exchange (LDS, no barrier: single-wave lockstep)
        if (!last) {
#pragma unroll
          for (int cf = 0; cf < 2; ++cf)
#pragma unroll
            for (int q = 0; q < 4; ++q) zex[rg][4 * la4 + q][16 * cf + la15] = accW[cf][q];
        }
      }
      if (!last) {
        u32 hp = 0;
#pragma unroll
        for (int ci = 0; ci < 2; ++ci) {
          float z4[4];
#pragma unroll
          for (int gi = 0; gi < 4; ++gi) {
            float s = xzv[ci][gi];
            if (t > 0) s += zex[rg][lrow][gi * 8 + c0 + ci];
            z4[gi] = s;
          }
          float ig = fsig(z4[0]);
          float fg = fsig(z4[1]);
          float gg = ftanh(z4[2]);
          float og = fsig(z4[3]);
          cst[ci] = fg * cst[ci] + ig * gg;
          float h = og * ftanh(cst[ci]);
          hp |= ((u32)f2bf(h)) << (16 * ci);
        }
        // fire-and-forget packed h store (2 cells = 4B)
        st32_dev((int *)(h0h + ((size_t)t * 32 + grow) * HDIM + 8 * g + c0), (int)hp);
      }
      asm volatile("s_waitcnt vmcnt(0)" ::: "memory");  // zeff (+h) at L3
      if (lane == 0) st32_dev(flags + fid, t + 1);      // zeff[t-1] complete
    }
  } else {
    // ---------------- layer 1 wave (512 slots, lag 2) ----------------
    float bef[2][4];
#pragma unroll
    for (int ci = 0; ci < 2; ++ci)
#pragma unroll
      for (int gi = 0; gi < 4; ++gi) bef[ci][gi] = beff[gi * HDIM + 8 * g + c0 + ci];
    for (int t = 0; t < SEQT; ++t) {
      // poll own producer's flag (single word; pre-satisfied in steady state)
      {
        const int *f0 = flags + fid;
        const int need0 = t + 2;
        for (long tries = 0;; ++tries) {
          int v = __hip_atomic_load(f0, __ATOMIC_RELAXED, __HIP_MEMORY_SCOPE_AGENT);
          if (v >= need0) break;
          if (tries > (1L << 22)) break;  // safety valve
          __builtin_amdgcn_s_sleep(1);
        }
      }
      // load zeff fragments (2 ld64) -> immediate unpack (rule 18)
      const u16 *rb = zeffR + (((size_t)(t & 15) * 256 + fid) << 9);
      i32x2 zp0 = ld64_dev(rb + (lane << 2));
      i32x2 zp1 = ld64_dev(rb + 256 + (lane << 2));
      asm volatile("s_waitcnt vmcnt(0)" ::: "memory");
      __builtin_amdgcn_sched_barrier(0);
      float zf[2][4];
      zf[0][0] = bf2f((u16)((u32)zp0[0] & 0xffffu));
      zf[0][1] = bf2f((u16)((u32)zp0[0] >> 16));
      zf[0][2] = bf2f((u16)((u32)zp0[1] & 0xffffu));
      zf[0][3] = bf2f((u16)((u32)zp0[1] >> 16));
      zf[1][0] = bf2f((u16)((u32)zp1[0] & 0xffffu));
      zf[1][1] = bf2f((u16)((u32)zp1[0] >> 16));
      zf[1][2] = bf2f((u16)((u32)zp1[1] & 0xffffu));
      zf[1][3] = bf2f((u16)((u32)zp1[1] >> 16));
      f32x4 accW[2] = {};
      if (t > 0) {
        const u16 *pA = h1h + ((size_t)(t - 1) * 32 + 16 * rg) * HDIM;
#pragma unroll
        for (int ph = 0; ph < 2; ++ph) {
          s16x8 aw[16];
          for (long tries = 0;; ++tries) {  // sentinel spec-load
#pragma unroll
            for (int i = 0; i < 16; ++i)
              aw[i] = ld128_dev(pA + (size_t)la15 * HDIM + 512 * ph + 32 * i + 8 * la4);
            asm volatile("s_waitcnt vmcnt(0)" ::: "memory");
            __builtin_amdgcn_sched_barrier(0);  // rule 18
            u32 bad = 0;
#pragma unroll
            for (int i = 0; i < 16; ++i) bad |= sentq(aw[i]);
            if (__all(bad == 0)) break;
            if (tries > (1L << 17)) break;  // safety valve
            __builtin_amdgcn_s_sleep(2);
          }
#pragma unroll
          for (int i = 0; i < 16; ++i) {
#pragma unroll
            for (int cf = 0; cf < 2; ++cf) {
              int zc = 16 * cf + la15;
              int sl = (4 * (16 * ph + i) + la4) ^ (zc & 7);
              int boff = zc * 2048 + (sl << 4);
              accW[cf] = mfma16(aw[i], *(const s16x8 *)((const char *)sW + boff), accW[cf]);
            }
          }
        }
      }
      // flag1: ring slot consumed (zeff loads retired at the vmcnt above)
      if (lane == 0) st32_dev(flags + 256 + fid, t + 1);
      // z exchange: Wh acc + zeff fragments (same lane layout), LDS no barrier
#pragma unroll
      for (int cf = 0; cf < 2; ++cf)
#pragma unroll
        for (int q = 0; q < 4; ++q)
          zex[rg][4 * la4 + q][16 * cf + la15] = accW[cf][q] + zf[cf][q];
      u32 hp = 0;
#pragma unroll
      for (int ci = 0; ci < 2; ++ci) {
        float z4[4];
#pragma unroll
        for (int gi = 0; gi < 4; ++gi)
          z4[gi] = bef[ci][gi] + zex[rg][lrow][gi * 8 + c0 + ci];
        float ig = fsig(z4[0]);
        float fg = fsig(z4[1]);
        float gg = ftanh(z4[2]);
        float og = fsig(z4[3]);
        cst[ci] = fg * cst[ci] + ig * gg;
        float h = og * ftanh(cst[ci]);
        hp |= ((u32)f2bf(h)) << (16 * ci);
      }
      st32_dev((int *)(h1h + ((size_t)t * 32 + grow) * HDIM + 8 * g + c0), (int)hp);  // fire-and-forget
    }
  }
}

// ---------------- host launcher ----------------
extern "C" void kernel_launch(void *const *d_in, const int *in_sizes, int n_in,
                              void *d_out, int out_size, void *d_ws, size_t ws_size,
                              hipStream_t stream) {
  const int *tokens = (const int *)d_in[0];
  const float *embed = (const float *)d_in[1];
  const float *Wx0 = (const float *)d_in[2];
  const float *Wh0 = (const float *)d_in[3];
  const float *b0 = (const float *)d_in[4];
  const float *Wfc0 = (const float *)d_in[5];
  const float *bfc0 = (const float *)d_in[6];
  const float *Wx1 = (const float *)d_in[7];
  const float *Wh1 = (const float *)d_in[8];
  const float *b1 = (const float *)d_in[9];
  const float *Wfc1 = (const float *)d_in[10];
  const float *bfc1 = (const float *)d_in[11];

  constexpr size_t NEED = 255856640;  // ~244 MiB (unchanged from validated R1)
  if (ws_size < NEED) {
    fprintf(stderr, "RNNLM kernel: ws too small (%zu < %zu)\n", ws_size, NEED);
    return;
  }
  char *ws = (char *)d_ws;
  u16 *xz0 = (u16 *)(ws + 0);           // [16384][4096] bf16, rows m=b*T+t
  u16 *h0h = (u16 *)(ws + 134217728);   // h0 hist [512][32][1024] bf16 (32 MB)
  u16 *h1h = (u16 *)(ws + 167772160);   // h1 hist (32 MB)
  u16 *x0hi = (u16 *)(ws + 201326592);  // 16 MB, dead after xz0 GEMM
  u16 *x0lo = (u16 *)(ws + 218103808);  // 16 MB, dead after xz0 GEMM
  // carved into the x0hi region AFTER the xz0 GEMM (stream-ordered):
  u16 *Weff = (u16 *)(ws + 201326592);      // [1024][4096] bf16 (8 MB)
  u16 *Wfc0hi = (u16 *)(ws + 209715200);    // [1024][512] (1 MB)
  u16 *Wfc0lo = (u16 *)(ws + 210763776);    // 1 MB
  u16 *WfcT1hi = (u16 *)(ws + 211812352);   // [512][1024] (1 MB)
  u16 *WfcT1lo = (u16 *)(ws + 212860928);   // 1 MB
  float *beff = (float *)(ws + 213909504);  // [4096] f32 (16 KB)
  int *flags = (int *)(ws + 213925888);     // [512] (2 KB)
  // zeffR ring [16][256 fid][512 u16] = 4 MB, in dead x0lo region.
  u16 *zeffR = (u16 *)(ws + 218103808);
  // own regions (live until their consumer GEMMs):
  u16 *WxT0hi = (u16 *)(ws + 234881024);  // [4096][512] (4 MB)
  u16 *WxT0lo = (u16 *)(ws + 239075328);
  u16 *WxT1hi = (u16 *)(ws + 243269632);  // [4096][512] (4 MB)
  u16 *WxT1lo = (u16 *)(ws + 247463936);  // ends 251658240

  // sentinel-fill the h buffers (h0h+h1h contiguous 64 MB) — EVERY launch
  (void)hipMemsetAsync(h0h, 0xFF, 67108864, stream);

  // prepack (regions disjoint from x0)
  k_packT<<<dim3(G4H / 32, DEMB / 32), dim3(32, 8), 0, stream>>>(Wx0, WxT0hi, WxT0lo, DEMB, G4H);
  k_packT<<<dim3(G4H / 32, DEMB / 32), dim3(32, 8), 0, stream>>>(Wx1, WxT1hi, WxT1lo, DEMB, G4H);
  // x0 = embed[tokens] hi/lo
  k_gather_pack<<<4096, 256, 0, stream>>>(tokens, embed, x0hi, x0lo);
  // xz0 = x0 @ Wx0 + b0 -> bf16 (rows m = b*T + t)
  k_gemm<0, 0><<<dim3(128 * 32), 256, 0, stream>>>(x0hi, x0lo, WxT0hi, WxT0lo, b0, xz0,
                                                   16384, G4H, DEMB);
  // x0 now dead: build fused layer-1 input path in its place
  k_split<<<2048, 256, 0, stream>>>(Wfc0, Wfc0hi, Wfc0lo, HDIM * PDIM);
  k_packT<<<dim3(PDIM / 32, HDIM / 32), dim3(32, 8), 0, stream>>>(Wfc1, WfcT1hi, WfcT1lo, HDIM, PDIM);
  k_beff<<<16, 256, 0, stream>>>(bfc0, Wx1, b1, beff);
  (void)hipMemsetAsync(flags, 0, 512 * sizeof(int), stream);
  // Weff = Wfc0 @ Wx1 -> bf16 [1024][4096]  (A=Wfc0 hi/lo, B=WxT1 hi/lo)
  k_gemm<0, 0><<<dim3(8 * 32), 256, 0, stream>>>(Wfc0hi, Wfc0lo, WxT1hi, WxT1lo, nullptr, Weff,
                                                 1024, G4H, PDIM);
  // zero-sync pipelined both-layer recurrence (256 WGs x 128 thr)
  {
    const u16 *a0 = xz0; const float *a1 = Wh0; const float *a2 = Wh1;
    const u16 *a3 = Weff; const float *a4 = beff;
    u16 *a5 = h0h; u16 *a6 = h1h; u16 *a7 = zeffR; int *a8 = flags;
    void *args[] = {&a0, &a1, &a2, &a3, &a4, &a5, &a6, &a7, &a8};
    hipError_t e = hipLaunchCooperativeKernel((void *)k_recur_pipe, dim3(256), dim3(128), args, 0, stream);
    if (e != hipSuccess) fprintf(stderr, "coop launch failed: %d\n", (int)e);
  }
  // out = h1 @ Wfc1 + bfc1 -> f32 scattered to (B,T,P)  (A single bf16)
  k_gemm<2, 1><<<dim3(128 * 4), 256, 0, stream>>>(h1h, h1h, WfcT1hi, WfcT1lo, bfc1, d_out,
                                                  16384, PDIM, HDIM);
}

// Round 15
// 4847.874 us; speedup vs baseline: 1.4101x; 1.4101x over previous
//
#include <hip/hip_runtime.h>
#include <cstdio>
#include <cstdint>

typedef unsigned short u16;
typedef unsigned int u32;
typedef float f32x4 __attribute__((ext_vector_type(4)));
typedef short s16x8 __attribute__((ext_vector_type(8)));
typedef int i32x2 __attribute__((ext_vector_type(2)));

#define DI __device__ __forceinline__

// problem sizes
#define BATCH 32
#define SEQT 512
#define HDIM 1024
#define PDIM 512
#define DEMB 512
#define G4H 4096

// ---------------- bf16 helpers (RNE + hi/lo split) ----------------
DI u16 f2bf(float f) {
  u32 u = __float_as_uint(f);
  return (u16)((u + 0x7fffu + ((u >> 16) & 1u)) >> 16);
}
DI float bf2f(u16 h) { return __uint_as_float(((u32)h) << 16); }
DI void split2(float f, u16 &hi, u16 &lo) {
  hi = f2bf(f);
  lo = f2bf(f - bf2f(hi));  // exact residual capture to ~2^-17 rel
}
DI f32x4 mfma16(s16x8 a, s16x8 b, f32x4 c) {
  return __builtin_amdgcn_mfma_f32_16x16x32_bf16(a, b, c, 0, 0, 0);
}
DI void dma16(const void *g, void *l) {
  __builtin_amdgcn_global_load_lds((const __attribute__((address_space(1))) void *)g,
                                   (__attribute__((address_space(3))) void *)l, 16, 0, 0);
}
// device-scope (sc1) ops: bypass L1/L2, talk straight to the coherence point.
// RULE-18/20 DISCIPLINE: asm-load outputs consumed right after vmcnt(0)+
// sched_barrier(0); loads->vmcnt gap holds no heavy code.
// R12 LESSON: never put per-lane LDS atomics on the critical path.
DI s16x8 ld128_dev(const u16 *p) {
  s16x8 r;
  asm volatile("global_load_dwordx4 %0, %1, off sc1" : "=v"(r) : "v"(p));
  return r;
}
DI i32x2 ld64_dev(const u16 *p) {
  i32x2 r;
  asm volatile("global_load_dwordx2 %0, %1, off sc1" : "=v"(r) : "v"(p));
  return r;
}
DI void st16_dev(u16 *p, u16 v) {
  asm volatile("global_store_short %0, %1, off sc1" ::"v"(p), "v"((u32)v) : "memory");
}
DI void st32_dev(int *p, int v) {
  asm volatile("global_store_dword %0, %1, off sc1" ::"v"(p), "v"(v) : "memory");
}
DI void st64_dev(u16 *p, i32x2 v) {
  asm volatile("global_store_dwordx2 %0, %1, off sc1" ::"v"(p), "v"(v) : "memory");
}
// sentinel detector: any bf16 lane == 0xFFFF (unreachable from f2bf(finite))
DI u32 sentq(s16x8 v) {
  union U { s16x8 s; u32 d[4]; } u;
  u.s = v;
  u32 b = 0;
#pragma unroll
  for (int i = 0; i < 4; ++i)
    b |= (u32)(((u.d[i] & 0xffffu) == 0xffffu) || ((u.d[i] >> 16) == 0xffffu));
  return b;
}

// fast gate math: hardware exp2 + rcp (~1e-7 abs err on sigmoid/tanh outputs)
#if __has_builtin(__builtin_amdgcn_exp2f) && __has_builtin(__builtin_amdgcn_rcpf)
DI float fsig(float x) {
  return __builtin_amdgcn_rcpf(1.f + __builtin_amdgcn_exp2f(-1.4426950408889634f * x));
}
DI float ftanh(float x) {
  return 2.f * __builtin_amdgcn_rcpf(1.f + __builtin_amdgcn_exp2f(-2.8853900817779268f * x)) - 1.f;
}
#else
DI float fsig(float x) { return 1.f / (1.f + expf(-x)); }
DI float ftanh(float x) { return tanhf(x); }
#endif

// ---------------- embed gather -> x0 hi/lo planes ----------------
__global__ void k_gather_pack(const int *__restrict__ tokens, const float *__restrict__ embed,
                              u16 *__restrict__ xhi, u16 *__restrict__ xlo) {
  int idx = blockIdx.x * 256 + threadIdx.x;  // one thread per 8 elements
  int m = idx >> 6;                          // row 0..16383 (m = b*T + t)
  int k8 = (idx & 63) << 3;
  int tok = tokens[m];
  const float *src = embed + (size_t)tok * DEMB + k8;
  float4 a = *(const float4 *)src;
  float4 b = *(const float4 *)(src + 4);
  float v[8] = {a.x, a.y, a.z, a.w, b.x, b.y, b.z, b.w};
  union UV { u16 h[8]; int4 v; };
  UV uh, ul;
#pragma unroll
  for (int j = 0; j < 8; ++j) split2(v[j], uh.h[j], ul.h[j]);
  size_t o = (size_t)m * DEMB + k8;
  *(int4 *)(xhi + o) = uh.v;
  *(int4 *)(xlo + o) = ul.v;
}

// ------- transpose+split weights: W[K][N] f32 -> T[N][K] bf16 hi/lo -------
__global__ void k_packT(const float *__restrict__ W, u16 *__restrict__ Thi, u16 *__restrict__ Tlo,
                        int K, int N) {
  __shared__ float tile[32][33];
  int n0 = blockIdx.x * 32, k0 = blockIdx.y * 32;
  int tx = threadIdx.x, ty = threadIdx.y;  // (32,8)
#pragma unroll
  for (int i = 0; i < 4; ++i) tile[ty + 8 * i][tx] = W[(size_t)(k0 + ty + 8 * i) * N + n0 + tx];
  __syncthreads();
#pragma unroll
  for (int i = 0; i < 4; ++i) {
    int n = ty + 8 * i;
    u16 hi, lo;
    split2(tile[tx][n], hi, lo);
    size_t o = (size_t)(n0 + n) * K + k0 + tx;
    Thi[o] = hi;
    Tlo[o] = lo;
  }
}

// ------- elementwise hi/lo split (row-major, no transpose) -------
__global__ void k_split(const float *__restrict__ W, u16 *__restrict__ hi, u16 *__restrict__ lo,
                        int n) {
  int i = blockIdx.x * 256 + threadIdx.x;
  if (i < n) split2(W[i], hi[i], lo[i]);
}

// ------- beff = bfc0 @ Wx1 + b1  (f32 [4096]) -------
__global__ void k_beff(const float *__restrict__ bfc0, const float *__restrict__ Wx1,
                       const float *__restrict__ b1, float *__restrict__ beff) {
  int n = blockIdx.x * 256 + threadIdx.x;  // 4096
  float acc = b1[n];
  for (int j = 0; j < PDIM; ++j) acc += bfc0[j] * Wx1[(size_t)j * G4H + n];
  beff[n] = acc;
}

// ---------------- generic bf16x3 GEMM ----------------
// C[M][N] = A[M][K] * B^T-source[N][K] + bias, A/B given as bf16 hi/lo planes.
// OM: 0 = bf16 out, 2 = f32 out scattered to (B,T,P).
// SA: 1 = A is single bf16 (Alo ignored; plane 1 zero-filled once).
template <int OM, int SA>
__global__ __launch_bounds__(256, 2) void k_gemm(const u16 *__restrict__ Ahi, const u16 *__restrict__ Alo,
                                                 const u16 *__restrict__ Bhi, const u16 *__restrict__ Blo,
                                                 const float *__restrict__ bias, void *__restrict__ out0,
                                                 int M, int N, int K) {
  __shared__ u16 sP[4][128 * 64];  // planes: Ahi, Alo, Bhi, Blo (16KB each)
  const int tid = threadIdx.x;
  const int w = tid >> 6, lane = tid & 63;
  const int la15 = lane & 15, la4 = lane >> 4;
  const int nbn = N >> 7;
  const int bm = blockIdx.x / nbn, bn = blockIdx.x % nbn;
  const u16 *src = (w == 0) ? Ahi : (w == 1) ? Alo : (w == 2) ? Bhi : Blo;
  const int rowbase = (w < 2) ? bm * 128 : bn * 128;
  char *lds = (char *)&sP[w][0];

  if (SA) {  // zero the Alo plane once; its MFMAs then contribute +0
    for (int i = tid; i < 2048; i += 256) ((unsigned long long *)&sP[1][0])[i] = 0ULL;
  }

  f32x4 acc[2][8] = {};
  for (int kb = 0; kb < K; kb += 64) {
    if (!(SA && w == 1)) {
#pragma unroll
      for (int i = 0; i < 16; ++i) {
        int s = i * 64 + lane;            // 16B slot id
        int row = s >> 3;                 // 8 slots per 128B row
        int k16 = (s & 7) ^ (row & 7);    // inverse of read swizzle
        dma16(src + (size_t)(rowbase + row) * K + kb + k16 * 8, lds + i * 1024);
      }
    }
    asm volatile("s_waitcnt vmcnt(0)" ::: "memory");
    __syncthreads();
#pragma unroll
    for (int ksl = 0; ksl < 2; ++ksl) {
      s16x8 ah[2], al[2];
#pragma unroll
      for (int rf = 0; rf < 2; ++rf) {
        int row = 32 * w + 16 * rf + la15;
        int slot = row * 8 + ((4 * ksl + la4) ^ (row & 7));
        ah[rf] = *(const s16x8 *)((const char *)&sP[0][0] + slot * 16);
        al[rf] = *(const s16x8 *)((const char *)&sP[1][0] + slot * 16);
      }
#pragma unroll
      for (int cf = 0; cf < 8; ++cf) {
        int col = 16 * cf + la15;
        int slot = col * 8 + ((4 * ksl + la4) ^ (col & 7));
        s16x8 bh = *(const s16x8 *)((const char *)&sP[2][0] + slot * 16);
        s16x8 bl = *(const s16x8 *)((const char *)&sP[3][0] + slot * 16);
#pragma unroll
        for (int rf = 0; rf < 2; ++rf) {
          acc[rf][cf] = mfma16(ah[rf], bh, acc[rf][cf]);
          acc[rf][cf] = mfma16(ah[rf], bl, acc[rf][cf]);
          acc[rf][cf] = mfma16(al[rf], bh, acc[rf][cf]);
        }
      }
    }
    __syncthreads();
  }
  // epilogue: D[r][c], r = 4*(lane>>4)+q (M), c = lane&15 (N)  [m89-verified]
#pragma unroll
  for (int rf = 0; rf < 2; ++rf) {
#pragma unroll
    for (int cf = 0; cf < 8; ++cf) {
      int c = bn * 128 + 16 * cf + la15;
      float bv = bias ? bias[c] : 0.f;
#pragma unroll
      for (int q = 0; q < 4; ++q) {
        int r = bm * 128 + 32 * w + 16 * rf + 4 * la4 + q;
        float v = acc[rf][cf][q] + bv;
        if (OM == 0) {
          ((u16 *)out0)[(size_t)r * N + c] = f2bf(v);
        } else {
          int b2 = r & 31, tt = r >> 5;  // A rows are m = t*32 + b
          ((float *)out0)[((size_t)b2 * SEQT + tt) * PDIM + c] = v;
        }
      }
    }
  }
}

// ---------------- pipelined 2-layer persistent LSTM recurrence (R13 best) ----------------
// R11 design (sentinel h handshake, flags for zeff ring freshness) with the
// zeff CROSS-WAVE REDUCTION MOVED TO L1 (which has slack — it idles on flag0):
//  L0: after each rt MFMA block, packs its accE f32x4 -> 4 bf16 and stores ONE
//      coalesced st64 per (rt,cf) into a per-wave ring block.
//  L1: thread tid loads partials for rtcf=tid>>6 from all 4 producer waves
//      (4 coalesced ld64), sums after vmcnt (immediate unpack -> LDS zE),
//      gates read zE. Ring [16][128][4][4][64] i32x2 = 16 MB (dead x0lo).
//  Backpressure: slot reuse after 16 steps -> every 8 steps L0 requires
//  flag1 >= t-9 (steady lag ~2 -> never blocks).
__global__ __launch_bounds__(256, 1) void k_recur_pipe(
    const u16 *__restrict__ xz0, const float *__restrict__ Wh0, const float *__restrict__ Wh1,
    const u16 *__restrict__ Weff, const float *__restrict__ beff,
    u16 *h0h, u16 *h1h, u16 *zeffR, int *flags) {
  __shared__ u16 sW[32 * 1024];      // 64 KB: layer's Wh slice [zc][k] swizzled
  __shared__ u16 sE[32 * 1024];      // 64 KB: L0's Weff slice (unused by L1)
  __shared__ float zacc[4][32][33];  // per-wave K-partials (+1 col pad)
  __shared__ float zE[32][33];       // L1: summed zeff [row][zc]
  __shared__ float sC[256];          // cell state c[32 rows][8 cols]
  const int tid = threadIdx.x;
  const int w = tid >> 6, lane = tid & 63;
  const int la15 = lane & 15, la4 = lane >> 4;
  const int wg = blockIdx.x;
  const int layer = wg >> 7;
  const int g = wg & 127;  // 8 h-cols: [8g, 8g+8)

  // stage weights (single bf16, swizzled), once per launch
  const float *Wh = layer ? Wh1 : Wh0;
  for (int i2 = tid; i2 < 32 * 1024; i2 += 256) {
    int zc = i2 & 31;
    int k = i2 >> 5;
    int gcol = (zc >> 3) * HDIM + 8 * g + (zc & 7);
    int boff = zc * 2048 + ((((k >> 3) ^ (zc & 7))) << 4) + (k & 7) * 2;
    *(u16 *)((char *)sW + boff) = f2bf(Wh[(size_t)k * G4H + gcol]);
    if (!layer) *(u16 *)((char *)sE + boff) = Weff[(size_t)k * G4H + gcol];
  }
  sC[tid] = 0.f;
  __syncthreads();

  const int r_g = tid >> 3, hc = tid & 7;  // gate coords: 32 rows x 8 cols
  const int ks0 = 8 * w;                   // wave's k-slice (256 k)

  if (!layer) {
    // ---------------- layer 0 (513 slots) ----------------
    for (int t = 0; t <= SEQT; ++t) {
      const bool last = (t == SEQT);
      float xzv[4] = {0.f, 0.f, 0.f, 0.f};
      if (!last) {
        const u16 *px = xz0 + ((size_t)r_g * SEQT + t) * G4H + 8 * g + hc;
#pragma unroll
        for (int gi = 0; gi < 4; ++gi) xzv[gi] = bf2f(px[(size_t)gi * HDIM]);
      }
      // rare ring backpressure (ring 16 deep): every 8 steps
      if (w == 0 && (t & 7) == 0 && t >= 16) {
        const int *f1 = flags + 128 + lane;
        const int bp = t - 9;
        for (long tries = 0;; ++tries) {
          int c = __hip_atomic_load(f1, __ATOMIC_RELAXED, __HIP_MEMORY_SCOPE_AGENT);
          int d = __hip_atomic_load(f1 + 64, __ATOMIC_RELAXED, __HIP_MEMORY_SCOPE_AGENT);
          if (__all(c >= bp && d >= bp)) break;
          if (tries > (1L << 22)) break;  // safety valve
          __builtin_amdgcn_s_sleep(1);
        }
      }
      if (t > 0) {
        const u16 *pA = h0h + (size_t)(t - 1) * 32 * HDIM;
        // speculative load of h0[t-1] with sentinel validation (per wave)
        s16x8 aw0[8], aw1[8];
        for (long tries = 0;; ++tries) {
#pragma unroll
          for (int j8 = 0; j8 < 8; ++j8)
            aw0[j8] = ld128_dev(pA + (size_t)la15 * HDIM + 32 * (ks0 + j8) + 8 * la4);
#pragma unroll
          for (int j8 = 0; j8 < 8; ++j8)
            aw1[j8] = ld128_dev(pA + (size_t)(16 + la15) * HDIM + 32 * (ks0 + j8) + 8 * la4);
          asm volatile("s_waitcnt vmcnt(0)" ::: "memory");
          __builtin_amdgcn_sched_barrier(0);  // rule 18
          u32 bad = 0;
#pragma unroll
          for (int j8 = 0; j8 < 8; ++j8) bad |= sentq(aw0[j8]) | sentq(aw1[j8]);
          if (__all(bad == 0)) break;
          if (tries > (1L << 17)) break;  // safety valve
          __builtin_amdgcn_s_sleep(2);
        }
        // per-wave ring block base (u16 units): [slot][g][w][rtcf][lane*4]
        u16 *zb = zeffR + ((((size_t)((t - 1) & 15) * 128 + g) << 12) + (w << 10));
#pragma unroll
        for (int rt = 0; rt < 2; ++rt) {
          f32x4 acc0[2] = {}, accE[2] = {};
#pragma unroll
          for (int j8 = 0; j8 < 8; ++j8) {
            s16x8 a = rt ? aw1[j8] : aw0[j8];
#pragma unroll
            for (int cf = 0; cf < 2; ++cf) {
              int zc = 16 * cf + la15;
              int sl = (4 * (ks0 + j8) + la4) ^ (zc & 7);
              int boff = zc * 2048 + (sl << 4);
              if (!last) acc0[cf] = mfma16(a, *(const s16x8 *)((const char *)sW + boff), acc0[cf]);
              accE[cf] = mfma16(a, *(const s16x8 *)((const char *)sE + boff), accE[cf]);
            }
          }
#pragma unroll
          for (int cf = 0; cf < 2; ++cf) {
            if (!last) {
#pragma unroll
              for (int q = 0; q < 4; ++q)
                zacc[w][16 * rt + 4 * la4 + q][16 * cf + la15] = acc0[cf][q];
            }
            // pack per-wave zeff partial (4 bf16) -> one coalesced 8B store
            i32x2 pk;
            pk[0] = (int)(((u32)f2bf(accE[cf][1]) << 16) | (u32)f2bf(accE[cf][0]));
            pk[1] = (int)(((u32)f2bf(accE[cf][3]) << 16) | (u32)f2bf(accE[cf][2]));
            st64_dev(zb + ((rt * 2 + cf) << 8) + (lane << 2), pk);
          }
        }
      }
      __syncthreads();  // zacc ready for gates
      if (!last) {
        float z4[4];
#pragma unroll
        for (int gi = 0; gi < 4; ++gi) {
          float s = xzv[gi];
          if (t > 0) {
            int zc = gi * 8 + hc;
            s += zacc[0][r_g][zc] + zacc[1][r_g][zc] + zacc[2][r_g][zc] + zacc[3][r_g][zc];
          }
          z4[gi] = s;
        }
        float ig = fsig(z4[0]);
        float fg = fsig(z4[1]);
        float gg = ftanh(z4[2]);
        float og = fsig(z4[3]);
        float c = fg * sC[tid] + ig * gg;
        sC[tid] = c;
        float h = og * ftanh(c);
        // fire-and-forget: consumers detect via sentinel disappearance
        st16_dev(h0h + ((size_t)t * 32 + r_g) * HDIM + 8 * g + hc, f2bf(h));
      }
      asm volatile("s_waitcnt vmcnt(0)" ::: "memory");  // own ring/h stores at L3
      __syncthreads();                                  // all waves drained; zacc reads done
      if (tid == 0) st32_dev(flags + g, t + 1);         // flag0: zeff[t-1] complete
    }
  } else {
    // ---------------- layer 1 (512 slots, lag 2) ----------------
    float bef[4];
#pragma unroll
    for (int gi = 0; gi < 4; ++gi) bef[gi] = beff[gi * HDIM + 8 * g + hc];
    // loader coords: this thread sums partials for rtcf = w, lane' = lane
    const int rtL = w >> 1, cfL = w & 1;
    for (int t = 0; t < SEQT; ++t) {
      s16x8 aw0[8], aw1[8];
      const u16 *pA = h1h + ((t > 0) ? (size_t)(t - 1) * 32 * HDIM : 0);
      if (t > 0) {  // attempt 1 issued early, overlaps the flag0 poll
#pragma unroll
        for (int j8 = 0; j8 < 8; ++j8)
          aw0[j8] = ld128_dev(pA + (size_t)la15 * HDIM + 32 * (ks0 + j8) + 8 * la4);
#pragma unroll
        for (int j8 = 0; j8 < 8; ++j8)
          aw1[j8] = ld128_dev(pA + (size_t)(16 + la15) * HDIM + 32 * (ks0 + j8) + 8 * la4);
      }
      // per-wave flag0 poll (zeff ring freshness); pre-satisfied in steady state
      {
        const int *f0 = flags + lane;
        const int need0 = t + 2;
        for (long tries = 0;; ++tries) {
          int a = __hip_atomic_load(f0, __ATOMIC_RELAXED, __HIP_MEMORY_SCOPE_AGENT);
          int b = __hip_atomic_load(f0 + 64, __ATOMIC_RELAXED, __HIP_MEMORY_SCOPE_AGENT);
          if (__all(a >= need0 && b >= need0)) break;
          if (tries > (1L << 22)) break;  // safety valve
          __builtin_amdgcn_s_sleep(1);
        }
      }
      // load this thread's 4 producer-wave partials (coalesced 8B each)
      const u16 *rb = zeffR + ((((size_t)(t & 15) * 128 + g) << 12) + (w << 8) + (lane << 2));
      i32x2 zp0 = ld64_dev(rb);
      i32x2 zp1 = ld64_dev(rb + 1024);
      i32x2 zp2 = ld64_dev(rb + 2048);
      i32x2 zp3 = ld64_dev(rb + 3072);
      asm volatile("s_waitcnt vmcnt(0)" ::: "memory");
      __builtin_amdgcn_sched_barrier(0);  // rule 18
      {  // unpack+sum NOW, park in LDS (no long-lived asm outputs)
        float s0 = bf2f((u16)((u32)zp0[0] & 0xffffu)) + bf2f((u16)((u32)zp1[0] & 0xffffu)) +
                   bf2f((u16)((u32)zp2[0] & 0xffffu)) + bf2f((u16)((u32)zp3[0] & 0xffffu));
        float s1 = bf2f((u16)((u32)zp0[0] >> 16)) + bf2f((u16)((u32)zp1[0] >> 16)) +
                   bf2f((u16)((u32)zp2[0] >> 16)) + bf2f((u16)((u32)zp3[0] >> 16));
        float s2 = bf2f((u16)((u32)zp0[1] & 0xffffu)) + bf2f((u16)((u32)zp1[1] & 0xffffu)) +
                   bf2f((u16)((u32)zp2[1] & 0xffffu)) + bf2f((u16)((u32)zp3[1] & 0xffffu));
        float s3 = bf2f((u16)((u32)zp0[1] >> 16)) + bf2f((u16)((u32)zp1[1] >> 16)) +
                   bf2f((u16)((u32)zp2[1] >> 16)) + bf2f((u16)((u32)zp3[1] >> 16));
        int zcL = 16 * cfL + la15, rowL = 16 * rtL + 4 * la4;
        zE[rowL + 0][zcL] = s0;
        zE[rowL + 1][zcL] = s1;
        zE[rowL + 2][zcL] = s2;
        zE[rowL + 3][zcL] = s3;
      }
      if (t > 0) {
        // sentinel validation of h1[t-1]; retry reissues the 16 loads
        for (long tries = 0;; ++tries) {
          u32 bad = 0;
#pragma unroll
          for (int j8 = 0; j8 < 8; ++j8) bad |= sentq(aw0[j8]) | sentq(aw1[j8]);
          if (__all(bad == 0)) break;
          if (tries > (1L << 17)) break;  // safety valve
          __builtin_amdgcn_s_sleep(2);
#pragma unroll
          for (int j8 = 0; j8 < 8; ++j8)
            aw0[j8] = ld128_dev(pA + (size_t)la15 * HDIM + 32 * (ks0 + j8) + 8 * la4);
#pragma unroll
          for (int j8 = 0; j8 < 8; ++j8)
            aw1[j8] = ld128_dev(pA + (size_t)(16 + la15) * HDIM + 32 * (ks0 + j8) + 8 * la4);
          asm volatile("s_waitcnt vmcnt(0)" ::: "memory");
          __builtin_amdgcn_sched_barrier(0);
        }
#pragma unroll
        for (int rt = 0; rt < 2; ++rt) {
          f32x4 acc0[2] = {};
#pragma unroll
          for (int j8 = 0; j8 < 8; ++j8) {
            s16x8 a = rt ? aw1[j8] : aw0[j8];
#pragma unroll
            for (int cf = 0; cf < 2; ++cf) {
              int zc = 16 * cf + la15;
              int sl = (4 * (ks0 + j8) + la4) ^ (zc & 7);
              int boff = zc * 2048 + (sl << 4);
              acc0[cf] = mfma16(a, *(const s16x8 *)((const char *)sW + boff), acc0[cf]);
            }
          }
#pragma unroll
          for (int cf = 0; cf < 2; ++cf)
#pragma unroll
            for (int q = 0; q < 4; ++q)
              zacc[w][16 * rt + 4 * la4 + q][16 * cf + la15] = acc0[cf][q];
        }
      }
      __syncthreads();  // zacc+zE ready; ring reads retired (per-wave vmcnt above)
      if (tid == 0) st32_dev(flags + 128 + g, t + 1);  // flag1: ring slot consumed
      {
        float z4[4];
#pragma unroll
        for (int gi = 0; gi < 4; ++gi) {
          int zc = gi * 8 + hc;
          float s = bef[gi] + zE[r_g][zc];
          if (t > 0)
            s += zacc[0][r_g][zc] + zacc[1][r_g][zc] + zacc[2][r_g][zc] + zacc[3][r_g][zc];
          z4[gi] = s;
        }
        float ig = fsig(z4[0]);
        float fg = fsig(z4[1]);
        float gg = ftanh(z4[2]);
        float og = fsig(z4[3]);
        float c = fg * sC[tid] + ig * gg;
        sC[tid] = c;
        float h = og * ftanh(c);
        st16_dev(h1h + ((size_t)t * 32 + r_g) * HDIM + 8 * g + hc, f2bf(h));  // fire-and-forget
      }
      __syncthreads();  // zacc/zE protect for next iteration
    }
  }
}

// ---------------- host launcher ----------------
extern "C" void kernel_launch(void *const *d_in, const int *in_sizes, int n_in,
                              void *d_out, int out_size, void *d_ws, size_t ws_size,
                              hipStream_t stream) {
  const int *tokens = (const int *)d_in[0];
  const float *embed = (const float *)d_in[1];
  const float *Wx0 = (const float *)d_in[2];
  const float *Wh0 = (const float *)d_in[3];
  const float *b0 = (const float *)d_in[4];
  const float *Wfc0 = (const float *)d_in[5];
  const float *bfc0 = (const float *)d_in[6];
  const float *Wx1 = (const float *)d_in[7];
  const float *Wh1 = (const float *)d_in[8];
  const float *b1 = (const float *)d_in[9];
  const float *Wfc1 = (const float *)d_in[10];
  const float *bfc1 = (const float *)d_in[11];

  constexpr size_t NEED = 255856640;  // ~244 MiB (unchanged from validated R1)
  if (ws_size < NEED) {
    fprintf(stderr, "RNNLM kernel: ws too small (%zu < %zu)\n", ws_size, NEED);
    return;
  }
  char *ws = (char *)d_ws;
  u16 *xz0 = (u16 *)(ws + 0);           // [16384][4096] bf16, rows m=b*T+t
  u16 *h0h = (u16 *)(ws + 134217728);   // h0 hist [512][32][1024] bf16 (32 MB)
  u16 *h1h = (u16 *)(ws + 167772160);   // h1 hist (32 MB)
  u16 *x0hi = (u16 *)(ws + 201326592);  // 16 MB, dead after xz0 GEMM
  u16 *x0lo = (u16 *)(ws + 218103808);  // 16 MB, dead after xz0 GEMM
  // carved into the x0hi region AFTER the xz0 GEMM (stream-ordered):
  u16 *Weff = (u16 *)(ws + 201326592);      // [1024][4096] bf16 (8 MB)
  u16 *Wfc0hi = (u16 *)(ws + 209715200);    // [1024][512] (1 MB)
  u16 *Wfc0lo = (u16 *)(ws + 210763776);    // 1 MB
  u16 *WfcT1hi = (u16 *)(ws + 211812352);   // [512][1024] (1 MB)
  u16 *WfcT1lo = (u16 *)(ws + 212860928);   // 1 MB
  float *beff = (float *)(ws + 213909504);  // [4096] f32 (16 KB)
  int *flags = (int *)(ws + 213925888);     // [256] (1 KB)
  // zeffR ring [16][128][4 w][4 rtcf][64 lane] i32x2 = 16 MB, in dead x0lo.
  u16 *zeffR = (u16 *)(ws + 218103808);     // ends 234881024 (= WxT0hi start)
  // own regions (live until their consumer GEMMs):
  u16 *WxT0hi = (u16 *)(ws + 234881024);  // [4096][512] (4 MB)
  u16 *WxT0lo = (u16 *)(ws + 239075328);
  u16 *WxT1hi = (u16 *)(ws + 243269632);  // [4096][512] (4 MB)
  u16 *WxT1lo = (u16 *)(ws + 247463936);  // ends 251658240

  // sentinel-fill the h buffers (h0h+h1h contiguous 64 MB) — EVERY launch
  (void)hipMemsetAsync(h0h, 0xFF, 67108864, stream);

  // prepack (regions disjoint from x0)
  k_packT<<<dim3(G4H / 32, DEMB / 32), dim3(32, 8), 0, stream>>>(Wx0, WxT0hi, WxT0lo, DEMB, G4H);
  k_packT<<<dim3(G4H / 32, DEMB / 32), dim3(32, 8), 0, stream>>>(Wx1, WxT1hi, WxT1lo, DEMB, G4H);
  // x0 = embed[tokens] hi/lo
  k_gather_pack<<<4096, 256, 0, stream>>>(tokens, embed, x0hi, x0lo);
  // xz0 = x0 @ Wx0 + b0 -> bf16 (rows m = b*T + t)
  k_gemm<0, 0><<<dim3(128 * 32), 256, 0, stream>>>(x0hi, x0lo, WxT0hi, WxT0lo, b0, xz0,
                                                   16384, G4H, DEMB);
  // x0 now dead: build fused layer-1 input path in its place
  k_split<<<2048, 256, 0, stream>>>(Wfc0, Wfc0hi, Wfc0lo, HDIM * PDIM);
  k_packT<<<dim3(PDIM / 32, HDIM / 32), dim3(32, 8), 0, stream>>>(Wfc1, WfcT1hi, WfcT1lo, HDIM, PDIM);
  k_beff<<<16, 256, 0, stream>>>(bfc0, Wx1, b1, beff);
  (void)hipMemsetAsync(flags, 0, 256 * sizeof(int), stream);
  // Weff = Wfc0 @ Wx1 -> bf16 [1024][4096]  (A=Wfc0 hi/lo, B=WxT1 hi/lo)
  k_gemm<0, 0><<<dim3(8 * 32), 256, 0, stream>>>(Wfc0hi, Wfc0lo, WxT1hi, WxT1lo, nullptr, Weff,
                                                 1024, G4H, PDIM);
  // pipelined both-layer recurrence (one coop dispatch, 256 thr/WG)
  {
    const u16 *a0 = xz0; const float *a1 = Wh0; const float *a2 = Wh1;
    const u16 *a3 = Weff; const float *a4 = beff;
    u16 *a5 = h0h; u16 *a6 = h1h; u16 *a7 = zeffR; int *a8 = flags;
    void *args[] = {&a0, &a1, &a2, &a3, &a4, &a5, &a6, &a7, &a8};
    hipError_t e = hipLaunchCooperativeKernel((void *)k_recur_pipe, dim3(256), dim3(256), args, 0, stream);
    if (e != hipSuccess) fprintf(stderr, "coop launch failed: %d\n", (int)e);
  }
  // out = h1 @ Wfc1 + bfc1 -> f32 scattered to (B,T,P)  (A single bf16)
  k_gemm<2, 1><<<dim3(128 * 4), 256, 0, stream>>>(h1h, h1h, WfcT1hi, WfcT1lo, bfc1, d_out,
                                                  16384, PDIM, HDIM);
}